// Round 4
// baseline (4407.250 us; speedup 1.0000x reference)
//
#include <hip/hip_runtime.h>
#include <cstdint>

#define B_IMG 32
#define N_PRI 24564
#define N_CLS 81
#define N_FG  80
#define PRE   200
#define MAXD  100
#define NBINS 1024
#define CANDS 512
#define SNAP_ULPS 2

#define SCORE_THR_F 0.01f
#define NMS_THR_D   0.45
#define CENTER_VAR_D 0.1
#define SIZE_VAR_D   0.2

// ---------------- Stage A: decode boxes (f64) ----------------
__global__ void decode_kernel(const float* __restrict__ bbox,
                              const float* __restrict__ priors,
                              double* __restrict__ boxes) {
  int n = blockIdx.x * blockDim.x + threadIdx.x;
  int b = blockIdx.y;
  if (n >= N_PRI) return;
  float4 loc = ((const float4*)bbox)[(size_t)b * N_PRI + n];
  float4 pr  = ((const float4*)priors)[n];
  double cx = ((double)loc.x * CENTER_VAR_D) * (double)pr.z + (double)pr.x;
  double cy = ((double)loc.y * CENTER_VAR_D) * (double)pr.w + (double)pr.y;
  double w  = exp((double)loc.z * SIZE_VAR_D) * (double)pr.z;
  double h  = exp((double)loc.w * SIZE_VAR_D) * (double)pr.w;
  double* o = boxes + ((size_t)b * N_PRI + n) * 4;
  double2 lo, hi;
  lo.x = cx - w * 0.5; lo.y = cy - h * 0.5;
  hi.x = cx + w * 0.5; hi.y = cy + h * 0.5;
  ((double2*)o)[0] = lo;
  ((double2*)o)[1] = hi;
}

// ---------------- Stage B: f64 softmax -> f32 scores, same-prior ulp-snap, transposed ----------------
__global__ void softmax_fg_kernel(const float* __restrict__ logits,
                                  float* __restrict__ fgT, int b0) {
  int n = blockIdx.x * blockDim.x + threadIdx.x;
  int lb = blockIdx.y;
  if (n >= N_PRI) return;
  int b = b0 + lb;
  const float* row = logits + ((size_t)b * N_PRI + n) * N_CLS;
  float m = row[0];
  for (int j = 1; j < N_CLS; ++j) m = fmaxf(m, row[j]);
  double dm = (double)m;
  double d = 0.0;
  for (int j = 0; j < N_CLS; ++j) d += exp((double)row[j] - dm);

  float ps[N_FG];
  for (int c = 1; c < N_CLS; ++c) {
    float p = (float)(exp((double)row[c] - dm) / d);   // correctly-rounded-f32 of f64 value
    ps[c - 1] = (p > SCORE_THR_F) ? p : 0.0f;
  }
  // Snap near-tied (<= SNAP_ULPS) cross-class scores of this prior to exact equality,
  // earliest class wins -> downstream stable index tie-break mimics np-f32 tie collapse.
  for (int c2 = 1; c2 < N_FG; ++c2) {
    float v2 = ps[c2];
    if (v2 <= 0.0f) continue;
    int u2 = (int)__float_as_uint(v2);
    for (int c1 = 0; c1 < c2; ++c1) {
      float v1 = ps[c1];
      if (v1 <= 0.0f) continue;
      int du = (int)__float_as_uint(v1) - u2;
      if (du <= SNAP_ULPS && du >= -SNAP_ULPS) { ps[c2] = v1; break; }
    }
  }
  float* outb = fgT + (size_t)lb * N_FG * N_PRI + n;
  for (int c = 0; c < N_FG; ++c)
    outb[(size_t)c * N_PRI] = ps[c];
}

// ---------------- Stage C: exact top-200 per (b, class), packed u64 keys ----------------
__global__ __launch_bounds__(256) void topk_kernel(const float* __restrict__ fgT,
                                                   float* __restrict__ topk_sc,
                                                   int* __restrict__ topk_idx, int b0) {
  __shared__ unsigned int hist[NBINS];
  __shared__ unsigned long long cand[CANDS];
  __shared__ unsigned int part[256];
  __shared__ int s_cut;
  __shared__ unsigned int s_cnt;
  int t = threadIdx.x;
  int c = blockIdx.x;
  int lb = blockIdx.y;
  int gb = b0 + lb;
  const float* src = fgT + ((size_t)lb * N_FG + c) * N_PRI;

  for (int i = t; i < NBINS; i += 256) hist[i] = 0;
  if (t == 0) s_cnt = 0;
  __syncthreads();

  for (int i = t; i < N_PRI; i += 256) {
    float v = src[i];
    if (v > 0.0f) atomicAdd(&hist[__float_as_uint(v) >> 21], 1u);
  }
  __syncthreads();

  unsigned s = 0;
  for (int j = 0; j < 4; ++j) s += hist[t * 4 + j];
  part[t] = s;
  __syncthreads();

  if (t == 0) {
    unsigned acc = 0; int cut = -1;
    for (int tb = 255; tb >= 0 && cut < 0; --tb) {
      unsigned pa = part[tb];
      if (acc + pa >= PRE) {
        for (int bin = tb * 4 + 3; bin >= tb * 4; --bin) {
          acc += hist[bin];
          if (acc >= PRE) { cut = bin; break; }
        }
      } else acc += pa;
    }
    s_cut = (cut < 0) ? 0 : cut;
  }
  __syncthreads();
  int cut = s_cut;

  for (int i = t; i < N_PRI; i += 256) {
    float v = src[i];
    if (v > 0.0f) {
      unsigned u = __float_as_uint(v);
      if ((int)(u >> 21) >= cut) {
        unsigned pos = atomicAdd(&s_cnt, 1u);
        if (pos < CANDS)
          cand[pos] = ((unsigned long long)u << 32) |
                      (unsigned long long)(0xFFFFFFFFu - (unsigned)i);
      }
    }
  }
  __syncthreads();
  unsigned cnt = s_cnt; if (cnt > CANDS) cnt = CANDS;
  for (int i = t; i < CANDS; i += 256)
    if ((unsigned)i >= cnt) cand[i] = 0ull;
  __syncthreads();

  // bitonic sort descending: value desc, then smaller index first
  for (int k = 2; k <= CANDS; k <<= 1) {
    for (int j = k >> 1; j > 0; j >>= 1) {
      for (int i = t; i < CANDS; i += 256) {
        int ixj = i ^ j;
        if (ixj > i) {
          unsigned long long a = cand[i], bb = cand[ixj];
          bool up = ((i & k) == 0);
          if (up ? (a < bb) : (a > bb)) { cand[i] = bb; cand[ixj] = a; }
        }
      }
      __syncthreads();
    }
  }

  if (t < PRE) {
    unsigned long long key = cand[t];
    float v = __uint_as_float((unsigned)(key >> 32));
    unsigned idx = 0xFFFFFFFFu - (unsigned)(key & 0xFFFFFFFFull);
    if (idx >= N_PRI) idx = 0;
    size_t o = ((size_t)gb * N_FG + c) * PRE + t;
    topk_sc[o] = v;
    topk_idx[o] = (int)idx;
  }
}

// ---------------- Stage D: greedy NMS per (b, class), one wave, f64 IoU ----------------
__global__ __launch_bounds__(64) void nms_kernel(const float* __restrict__ topk_sc,
                                                 const int* __restrict__ topk_idx,
                                                 const double* __restrict__ boxes,
                                                 float* __restrict__ cls_sc) {
  __shared__ double bx[PRE][4];
  __shared__ double ar[PRE];
  __shared__ float sc[PRE];
  __shared__ unsigned char supp[PRE];
  int t = threadIdx.x;
  int c = blockIdx.x, b = blockIdx.y;
  size_t base = ((size_t)b * N_FG + c) * PRE;

  for (int k = t; k < PRE; k += 64) {
    int idx = topk_idx[base + k];
    const double* bp = boxes + ((size_t)b * N_PRI + idx) * 4;
    double x1 = bp[0], y1 = bp[1], x2 = bp[2], y2 = bp[3];
    bx[k][0] = x1; bx[k][1] = y1; bx[k][2] = x2; bx[k][3] = y2;
    ar[k] = fmax(x2 - x1, 0.0) * fmax(y2 - y1, 0.0);
    sc[k] = topk_sc[base + k];
    supp[k] = 0;
  }
  __syncthreads();

  double mybx[4][4]; double mya[4]; bool mykeep[4];
  for (int r = 0; r < 4; ++r) {
    int k = t + r * 64;
    mykeep[r] = false;
    if (k < PRE) {
      mybx[r][0] = bx[k][0]; mybx[r][1] = bx[k][1];
      mybx[r][2] = bx[k][2]; mybx[r][3] = bx[k][3];
      mya[r] = ar[k];
    }
  }

  for (int i = 0; i < PRE; ++i) {
    bool keep_i = (sc[i] > 0.0f) && (supp[i] == 0);
    if ((i & 63) == t) mykeep[i >> 6] = keep_i;
    if (keep_i) {
      double x1 = bx[i][0], y1 = bx[i][1], x2 = bx[i][2], y2 = bx[i][3];
      double ai = ar[i];
      for (int r = 0; r < 4; ++r) {
        int k = t + r * 64;
        if (k < PRE && k > i) {
          double xx1 = fmax(x1, mybx[r][0]), yy1 = fmax(y1, mybx[r][1]);
          double xx2 = fmin(x2, mybx[r][2]), yy2 = fmin(y2, mybx[r][3]);
          double inter = fmax(xx2 - xx1, 0.0) * fmax(yy2 - yy1, 0.0);
          double uni = fmax(ai + mya[r] - inter, 1e-9);
          if (inter / uni > NMS_THR_D) supp[k] = 1;
        }
      }
    }
    __syncthreads();
  }

  for (int r = 0; r < 4; ++r) {
    int k = t + r * 64;
    if (k < PRE) cls_sc[base + k] = mykeep[r] ? sc[k] : 0.0f;
  }
}

// ---------------- Stage E: per-image top-100 + gather outputs ----------------
__global__ __launch_bounds__(256) void final_kernel(const float* __restrict__ cls_sc,
                                                    const int* __restrict__ topk_idx,
                                                    const double* __restrict__ boxes,
                                                    float* __restrict__ out) {
  __shared__ unsigned int hist[NBINS];
  __shared__ unsigned long long cand[CANDS];
  __shared__ unsigned int part[256];
  __shared__ int s_cut;
  __shared__ unsigned int s_cnt;
  const int M = N_FG * PRE;  // 16000
  int t = threadIdx.x, b = blockIdx.x;
  const float* src = cls_sc + (size_t)b * M;

  for (int i = t; i < NBINS; i += 256) hist[i] = 0;
  if (t == 0) s_cnt = 0;
  __syncthreads();

  for (int i = t; i < M; i += 256) {
    float v = src[i];
    if (v > 0.0f) atomicAdd(&hist[__float_as_uint(v) >> 21], 1u);
  }
  __syncthreads();

  unsigned s = 0;
  for (int j = 0; j < 4; ++j) s += hist[t * 4 + j];
  part[t] = s;
  __syncthreads();

  if (t == 0) {
    unsigned acc = 0; int cut = -1;
    for (int tb = 255; tb >= 0 && cut < 0; --tb) {
      unsigned pa = part[tb];
      if (acc + pa >= MAXD) {
        for (int bin = tb * 4 + 3; bin >= tb * 4; --bin) {
          acc += hist[bin];
          if (acc >= MAXD) { cut = bin; break; }
        }
      } else acc += pa;
    }
    s_cut = (cut < 0) ? 0 : cut;
  }
  __syncthreads();
  int cut = s_cut;

  for (int i = t; i < M; i += 256) {
    float v = src[i];
    if (v > 0.0f) {
      unsigned u = __float_as_uint(v);
      if ((int)(u >> 21) >= cut) {
        unsigned pos = atomicAdd(&s_cnt, 1u);
        if (pos < CANDS)
          cand[pos] = ((unsigned long long)u << 32) |
                      (unsigned long long)(0xFFFFFFFFu - (unsigned)i);
      }
    }
  }
  __syncthreads();
  unsigned cnt = s_cnt; if (cnt > CANDS) cnt = CANDS;
  for (int i = t; i < CANDS; i += 256)
    if ((unsigned)i >= cnt) cand[i] = 0ull;
  __syncthreads();

  for (int k = 2; k <= CANDS; k <<= 1) {
    for (int j = k >> 1; j > 0; j >>= 1) {
      for (int i = t; i < CANDS; i += 256) {
        int ixj = i ^ j;
        if (ixj > i) {
          unsigned long long a = cand[i], bb = cand[ixj];
          bool up = ((i & k) == 0);
          if (up ? (a < bb) : (a > bb)) { cand[i] = bb; cand[ixj] = a; }
        }
      }
      __syncthreads();
    }
  }

  if (t < MAXD) {
    unsigned long long key = cand[t];
    float v = __uint_as_float((unsigned)(key >> 32));
    unsigned f = 0xFFFFFFFFu - (unsigned)(key & 0xFFFFFFFFull);
    if (f >= (unsigned)M) f = 0;
    int c = (int)(f / PRE), k = (int)(f % PRE);
    int idx = topk_idx[((size_t)b * N_FG + c) * PRE + k];
    if (idx < 0 || idx >= N_PRI) idx = 0;
    const double* bp = boxes + ((size_t)b * N_PRI + idx) * 4;
    float4 bb = make_float4((float)bp[0], (float)bp[1], (float)bp[2], (float)bp[3]);
    ((float4*)out)[b * MAXD + t] = bb;                              // det_bx
    out[B_IMG * MAXD * 4 + b * MAXD + t] = v;                       // det_sc
    out[B_IMG * MAXD * 5 + b * MAXD + t] = (float)(c + 1);          // det_lb (as float)
  }
}

extern "C" void kernel_launch(void* const* d_in, const int* in_sizes, int n_in,
                              void* d_out, int out_size, void* d_ws, size_t ws_size,
                              hipStream_t stream) {
  const float* cls_logits = (const float*)d_in[0];
  const float* bbox_pred  = (const float*)d_in[1];
  const float* priors     = (const float*)d_in[2];
  float* out = (float*)d_out;

  double* boxes   = (double*)d_ws;                                    // B*N*4 f64
  float* topk_sc  = (float*)(boxes + (size_t)B_IMG * N_PRI * 4);      // B*80*200 f32
  int*   topk_idx = (int*)(topk_sc + (size_t)B_IMG * N_FG * PRE);     // B*80*200 i32
  float* cls_sc   = (float*)(topk_idx + (size_t)B_IMG * N_FG * PRE);  // B*80*200 f32
  float* fgT      = cls_sc + (size_t)B_IMG * N_FG * PRE;              // chunkB*80*N f32

  size_t persist_bytes = (size_t)((char*)fgT - (char*)d_ws);
  size_t per_b = (size_t)N_FG * N_PRI * sizeof(float);
  int chunkB = 1;
  if (ws_size > persist_bytes) {
    size_t cb = (ws_size - persist_bytes) / per_b;
    chunkB = (cb >= (size_t)B_IMG) ? B_IMG : (cb < 1 ? 1 : (int)cb);
  }

  decode_kernel<<<dim3((N_PRI + 255) / 256, B_IMG), 256, 0, stream>>>(
      bbox_pred, priors, boxes);

  for (int b0 = 0; b0 < B_IMG; b0 += chunkB) {
    int nb = (B_IMG - b0) < chunkB ? (B_IMG - b0) : chunkB;
    softmax_fg_kernel<<<dim3((N_PRI + 255) / 256, nb), 256, 0, stream>>>(
        cls_logits, fgT, b0);
    topk_kernel<<<dim3(N_FG, nb), 256, 0, stream>>>(
        fgT, topk_sc, topk_idx, b0);
  }

  nms_kernel<<<dim3(N_FG, B_IMG), 64, 0, stream>>>(
      topk_sc, topk_idx, boxes, cls_sc);

  final_kernel<<<B_IMG, 256, 0, stream>>>(
      cls_sc, topk_idx, boxes, out);
}